// Round 1
// baseline (6795.208 us; speedup 1.0000x reference)
//
#include <hip/hip_runtime.h>

#define N_NODES 100000
#define N_EDGES 1600000
#define NODE_F 64
#define EDGE_F 32
#define OUT_F 64
#define HIDDEN 128
#define IN_F 160   // 2*NODE_F + EDGE_F

// ---------------------------------------------------------------------------
// Kernel P: transpose W1 [IN_F][HIDDEN] -> W1T [HIDDEN][IN_F] so that the
// edge kernel reads layer-1 weight rows contiguously (uniform dwordx4 loads).
// ---------------------------------------------------------------------------
__global__ __launch_bounds__(256) void transpose_w1(const float* __restrict__ W1,
                                                    float* __restrict__ W1T) {
    int idx = blockIdx.x * 256 + threadIdx.x;
    if (idx < IN_F * HIDDEN) {
        int i = idx / HIDDEN;   // input-feature index
        int j = idx % HIDDEN;   // hidden index
        W1T[j * IN_F + i] = W1[idx];
    }
}

// ---------------------------------------------------------------------------
// Kernel E: one thread per edge. Gather features to registers, run the MLP
// streaming over hidden units (h_j consumed immediately), atomically
// accumulate the message into agg[receiver] and bump deg[receiver].
// ---------------------------------------------------------------------------
__global__ __launch_bounds__(256, 2) void edge_mlp_kernel(
    const float* __restrict__ nodes, const float* __restrict__ edges,
    const int* __restrict__ senders, const int* __restrict__ receivers,
    const float* __restrict__ W1T, const float* __restrict__ b1,
    const float* __restrict__ W2, const float* __restrict__ b2,
    float* __restrict__ agg, float* __restrict__ deg)
{
    const int e = blockIdx.x * 256 + threadIdx.x;   // grid is exact: E % 256 == 0
    const int s = senders[e];
    const int r = receivers[e];

    float x[IN_F];
    {
        const float4* ns = reinterpret_cast<const float4*>(nodes + (size_t)s * NODE_F);
        #pragma unroll
        for (int i = 0; i < NODE_F / 4; ++i) {
            float4 v = ns[i];
            x[4*i+0] = v.x; x[4*i+1] = v.y; x[4*i+2] = v.z; x[4*i+3] = v.w;
        }
        const float4* nr = reinterpret_cast<const float4*>(nodes + (size_t)r * NODE_F);
        #pragma unroll
        for (int i = 0; i < NODE_F / 4; ++i) {
            float4 v = nr[i];
            x[NODE_F + 4*i+0] = v.x; x[NODE_F + 4*i+1] = v.y;
            x[NODE_F + 4*i+2] = v.z; x[NODE_F + 4*i+3] = v.w;
        }
        const float4* ee = reinterpret_cast<const float4*>(edges + (size_t)e * EDGE_F);
        #pragma unroll
        for (int i = 0; i < EDGE_F / 4; ++i) {
            float4 v = ee[i];
            x[2*NODE_F + 4*i+0] = v.x; x[2*NODE_F + 4*i+1] = v.y;
            x[2*NODE_F + 4*i+2] = v.z; x[2*NODE_F + 4*i+3] = v.w;
        }
    }

    float msg[OUT_F];
    #pragma unroll
    for (int o = 0; o < OUT_F; ++o) msg[o] = b2[o];

    for (int j = 0; j < HIDDEN; ++j) {
        const float* __restrict__ w1row = W1T + j * IN_F;   // wave-uniform address
        float a0 = 0.f, a1 = 0.f, a2 = 0.f, a3 = 0.f;       // 4 chains hide fma latency
        #pragma unroll
        for (int i = 0; i < IN_F; i += 4) {
            a0 = fmaf(x[i+0], w1row[i+0], a0);
            a1 = fmaf(x[i+1], w1row[i+1], a1);
            a2 = fmaf(x[i+2], w1row[i+2], a2);
            a3 = fmaf(x[i+3], w1row[i+3], a3);
        }
        float h = (a0 + a1) + (a2 + a3) + b1[j];
        h = fmaxf(h, 0.f);
        const float* __restrict__ w2row = W2 + j * OUT_F;   // wave-uniform address
        #pragma unroll
        for (int o = 0; o < OUT_F; ++o) msg[o] = fmaf(h, w2row[o], msg[o]);
    }

    float* ar = agg + (size_t)r * OUT_F;
    #pragma unroll
    for (int o = 0; o < OUT_F; ++o) atomicAdd(ar + o, msg[o]);
    atomicAdd(deg + r, 1.0f);
}

// ---------------------------------------------------------------------------
// Kernel N: out[n] = agg[n]/max(deg[n],1) + nodes[n] @ Wn + bn
// ---------------------------------------------------------------------------
__global__ __launch_bounds__(256) void node_update_kernel(
    const float* __restrict__ nodes, const float* __restrict__ Wn,
    const float* __restrict__ bn, const float* __restrict__ agg,
    const float* __restrict__ deg, float* __restrict__ out)
{
    const int n = blockIdx.x * 256 + threadIdx.x;
    if (n >= N_NODES) return;

    float x[NODE_F];
    {
        const float4* nx = reinterpret_cast<const float4*>(nodes + (size_t)n * NODE_F);
        #pragma unroll
        for (int i = 0; i < NODE_F / 4; ++i) {
            float4 v = nx[i];
            x[4*i+0] = v.x; x[4*i+1] = v.y; x[4*i+2] = v.z; x[4*i+3] = v.w;
        }
    }

    float acc[OUT_F];
    #pragma unroll
    for (int o = 0; o < OUT_F; ++o) acc[o] = bn[o];

    for (int k = 0; k < NODE_F; ++k) {
        const float* __restrict__ wr = Wn + k * OUT_F;      // wave-uniform address
        #pragma unroll
        for (int o = 0; o < OUT_F; ++o) acc[o] = fmaf(x[k], wr[o], acc[o]);
    }

    const float invd = 1.0f / fmaxf(deg[n], 1.0f);
    const float4* ag = reinterpret_cast<const float4*>(agg + (size_t)n * OUT_F);
    float4* op = reinterpret_cast<float4*>(out + (size_t)n * OUT_F);
    #pragma unroll
    for (int i = 0; i < OUT_F / 4; ++i) {
        float4 a = ag[i];
        float4 rr;
        rr.x = fmaf(a.x, invd, acc[4*i+0]);
        rr.y = fmaf(a.y, invd, acc[4*i+1]);
        rr.z = fmaf(a.z, invd, acc[4*i+2]);
        rr.w = fmaf(a.w, invd, acc[4*i+3]);
        op[i] = rr;
    }
}

// ---------------------------------------------------------------------------
extern "C" void kernel_launch(void* const* d_in, const int* in_sizes, int n_in,
                              void* d_out, int out_size, void* d_ws, size_t ws_size,
                              hipStream_t stream) {
    const float* nodes     = (const float*)d_in[0];
    const float* edges     = (const float*)d_in[1];
    const int*   senders   = (const int*)  d_in[2];
    const int*   receivers = (const int*)  d_in[3];
    const float* W1        = (const float*)d_in[4];
    const float* b1        = (const float*)d_in[5];
    const float* W2        = (const float*)d_in[6];
    const float* b2        = (const float*)d_in[7];
    const float* Wn        = (const float*)d_in[8];
    const float* bn        = (const float*)d_in[9];
    float* out = (float*)d_out;

    char* ws = (char*)d_ws;
    const size_t agg_bytes = (size_t)N_NODES * OUT_F * sizeof(float);  // 25.6 MB
    const size_t deg_bytes = (size_t)N_NODES * sizeof(float);          // 0.4 MB
    float* agg = (float*)ws;
    float* deg = (float*)(ws + agg_bytes);
    float* W1T = (float*)(ws + agg_bytes + deg_bytes);                 // 80 KB

    // zero the atomic accumulators (ws is poisoned 0xAA before every call)
    hipMemsetAsync(ws, 0, agg_bytes + deg_bytes, stream);

    transpose_w1<<<(IN_F * HIDDEN + 255) / 256, 256, 0, stream>>>(W1, W1T);

    edge_mlp_kernel<<<N_EDGES / 256, 256, 0, stream>>>(
        nodes, edges, senders, receivers, W1T, b1, W2, b2, agg, deg);

    node_update_kernel<<<(N_NODES + 255) / 256, 256, 0, stream>>>(
        nodes, Wn, bn, agg, deg, out);
}